// Round 5
// baseline (229.008 us; speedup 1.0000x reference)
//
#include <hip/hip_runtime.h>
#include <math.h>

#define D128 128
#define ROWS 4

typedef unsigned int uint32;
typedef short bf16x8 __attribute__((ext_vector_type(8)));
typedef float f32x4 __attribute__((ext_vector_type(4)));

// fp32 -> bf16 (RNE)
__device__ __forceinline__ unsigned short bf16_of(float x) {
  uint32 u = __float_as_uint(x);
  return (unsigned short)((u + 0x7fffu + ((u >> 16) & 1u)) >> 16);
}
__device__ __forceinline__ uint32 pack_bf2(float x, float y) {
  uint32 bx = __float_as_uint(x);
  uint32 by = __float_as_uint(y);
  bx = (bx + 0x7fffu + ((bx >> 16) & 1u)) >> 16;
  by = (by + 0x7fffu + ((by >> 16) & 1u)) & 0xffff0000u;
  return bx | by;
}
__device__ __forceinline__ float bf_lo(uint32 u) { return __uint_as_float(u << 16); }
__device__ __forceinline__ float bf_hi(uint32 u) { return __uint_as_float(u & 0xffff0000u); }

// tanh(x) = 1 - 2/(1+exp(2x)) via v_exp + v_rcp
__device__ __forceinline__ float fast_tanh(float x) {
  float e = __expf(2.0f * x);
  float r = __builtin_amdgcn_rcpf(1.0f + e);
  return fmaf(-2.0f, r, 1.0f);
}

// ---------------------------------------------------------------------------
// prep_w: W1 [256][128] fp32 -> Wt[2][128][128] bf16, Wt[h][n][k] = W1[h*128+k][n]
// one-time transpose+convert (64 KB out), removes per-block W staging.
// ---------------------------------------------------------------------------
__global__ __launch_bounds__(256) void prep_w(const float* __restrict__ W1,
                                              unsigned short* __restrict__ Wt) {
  int t = blockIdx.x * 256 + threadIdx.x;   // 0..32767
  if (t >= 2 * D128 * D128) return;
  int h = t >> 14;
  int n = (t >> 7) & 127;
  int k = t & 127;
  Wt[t] = bf16_of(W1[(size_t)(h * D128 + k) * D128 + n]);
}

// ---------------------------------------------------------------------------
// seg_offsets: dst_idx sorted -> off[v] = first edge with dst >= v, off[N]=E.
// ---------------------------------------------------------------------------
__global__ __launch_bounds__(256) void seg_offsets_kernel(
    const int* __restrict__ dst_idx, int* __restrict__ off, int E, int N) {
  int e = blockIdx.x * 256 + threadIdx.x;
  if (e >= E) return;
  int d = dst_idx[e];
  int dprev = (e == 0) ? -1 : dst_idx[e - 1];
  for (int v = dprev + 1; v <= d; v++) off[v] = e;
  if (e == E - 1) {
    for (int v = d + 1; v <= N; v++) off[v] = E;
  }
}

// ---------------------------------------------------------------------------
// P_bf[M][128] (bf16) = X[M][128] @ W via MFMA 16x16x32 bf16.
// W pre-transposed bf16 in global (Wt[n][k]) -- read straight to B-frags
// (L1/L2-hot, 16 fully-used cache lines per wave-load). X staged in LDS
// (vectorized fp32->bf16). 128-row tile, wave = 32 rows x 128 cols.
// Optionally emits bf16 copy of X.
// ---------------------------------------------------------------------------
__global__ __launch_bounds__(256) void gemm_mfma(const float* __restrict__ X,
                                                 const unsigned short* __restrict__ Wt,
                                                 unsigned short* __restrict__ P_bf,
                                                 uint32* __restrict__ X_bf,  // or null
                                                 int M) {
  __shared__ unsigned short Xs[128][136];
  const int tid = threadIdx.x;
  const int row0 = blockIdx.x * 128;

  // stage X tile: 128 rows x 128 cols fp32 -> bf16 (+ optional global copy)
#pragma unroll
  for (int it = 0; it < 16; it++) {
    int f = tid + 256 * it;          // 0..4095 float4s
    int r = f >> 5;
    int c4 = (f & 31) * 4;
    int gr = row0 + r;
    float4 v = make_float4(0.f, 0.f, 0.f, 0.f);
    if (gr < M) v = *(const float4*)(X + (size_t)gr * D128 + c4);
    uint2 p;
    p.x = pack_bf2(v.x, v.y);
    p.y = pack_bf2(v.z, v.w);
    *(uint2*)(&Xs[r][c4]) = p;
    if (X_bf && gr < M) *(uint2*)(X_bf + (size_t)gr * 64 + (c4 >> 1)) = p;
  }
  __syncthreads();

  const int wave = tid >> 6;
  const int lane = tid & 63;
  const int m = lane & 15;
  const int quad = lane >> 4;

  f32x4 acc[2][8];
#pragma unroll
  for (int st = 0; st < 2; st++)
#pragma unroll
    for (int nt = 0; nt < 8; nt++) acc[st][nt] = (f32x4){0.f, 0.f, 0.f, 0.f};

#pragma unroll
  for (int kc = 0; kc < 4; kc++) {
    bf16x8 a0 = *(const bf16x8*)(&Xs[wave * 32 + m][kc * 32 + quad * 8]);
    bf16x8 a1 = *(const bf16x8*)(&Xs[wave * 32 + 16 + m][kc * 32 + quad * 8]);
#pragma unroll
    for (int nt = 0; nt < 8; nt++) {
      bf16x8 b = *(const bf16x8*)(Wt + (size_t)(nt * 16 + m) * D128 + kc * 32 + quad * 8);
      acc[0][nt] = __builtin_amdgcn_mfma_f32_16x16x32_bf16(a0, b, acc[0][nt], 0, 0, 0);
      acc[1][nt] = __builtin_amdgcn_mfma_f32_16x16x32_bf16(a1, b, acc[1][nt], 0, 0, 0);
    }
  }

  // C/D: col = lane&15, row = quad*4 + reg
#pragma unroll
  for (int st = 0; st < 2; st++) {
#pragma unroll
    for (int nt = 0; nt < 8; nt++) {
#pragma unroll
      for (int r = 0; r < 4; r++) {
        int grow = row0 + wave * 32 + st * 16 + quad * 4 + r;
        if (grow < M) P_bf[(size_t)grow * D128 + nt * 16 + m] = bf16_of(acc[st][nt][r]);
      }
    }
  }
}

// ---------------------------------------------------------------------------
// 16 lanes per edge: raw[e] = tanh(p_src[src]+p_dst[dst]) . w2 * ew[e]
// ---------------------------------------------------------------------------
__global__ __launch_bounds__(256) void edge_raw_kernel(
    const uint32* __restrict__ p_src_bf, const uint32* __restrict__ p_dst_bf,
    const float* __restrict__ w2, const float* __restrict__ ew,
    const int* __restrict__ src_idx, const int* __restrict__ dst_idx,
    float* __restrict__ raw, int E) {
  __shared__ float sw2[128];
  const int tid = threadIdx.x;
  if (tid < 128) sw2[tid] = w2[tid];
  __syncthreads();
  const int sub = tid & 15;   // lane within edge -> channels sub*8..+7
  const int e = blockIdx.x * 16 + (tid >> 4);
  if (e >= E) return;
  const int s = src_idx[e];
  const int d = dst_idx[e];
  uint4 us = *(const uint4*)(p_src_bf + (size_t)s * 64 + sub * 4);
  uint4 ud = *(const uint4*)(p_dst_bf + (size_t)d * 64 + sub * 4);
  float4 wA = *(const float4*)(&sw2[sub * 8]);
  float4 wB = *(const float4*)(&sw2[sub * 8 + 4]);
  float acc;
  acc = fast_tanh(bf_lo(us.x) + bf_lo(ud.x)) * wA.x;
  acc = fmaf(fast_tanh(bf_hi(us.x) + bf_hi(ud.x)), wA.y, acc);
  acc = fmaf(fast_tanh(bf_lo(us.y) + bf_lo(ud.y)), wA.z, acc);
  acc = fmaf(fast_tanh(bf_hi(us.y) + bf_hi(ud.y)), wA.w, acc);
  acc = fmaf(fast_tanh(bf_lo(us.z) + bf_lo(ud.z)), wB.x, acc);
  acc = fmaf(fast_tanh(bf_hi(us.z) + bf_hi(ud.z)), wB.y, acc);
  acc = fmaf(fast_tanh(bf_lo(us.w) + bf_lo(ud.w)), wB.z, acc);
  acc = fmaf(fast_tanh(bf_hi(us.w) + bf_hi(ud.w)), wB.w, acc);
#pragma unroll
  for (int o = 1; o <= 8; o <<= 1) acc += __shfl_xor(acc, o, 64);
  if (sub == 0) raw[e] = acc * ew[e];
}

// ---------------------------------------------------------------------------
// one 128-thread block (2 waves) per dst. off[] gives edge range (no search).
// ---------------------------------------------------------------------------
__global__ __launch_bounds__(128) void dst_agg_kernel(
    float* raw_attn, const uint32* __restrict__ h_src_bf2,
    const int* __restrict__ src_idx, const int* __restrict__ off,
    float* __restrict__ h_global) {
  const int v = blockIdx.x;
  const int tid = threadIdx.x;
  const int t2 = tid & 63;   // channel pair
  const int g = tid >> 6;    // wave id
  const int lo = off[v], hi = off[v + 1];
  const int deg = hi - lo;

  __shared__ float sred[2];
  __shared__ float sex[128];
  __shared__ int ssrc[128];
  __shared__ float sacc[64][2];

  // pass 1: max
  float lm = -INFINITY;
  for (int e = lo + tid; e < hi; e += 128) lm = fmaxf(lm, raw_attn[e]);
#pragma unroll
  for (int o = 32; o >= 1; o >>= 1) lm = fmaxf(lm, __shfl_xor(lm, o, 64));
  if (t2 == 0) sred[g] = lm;
  __syncthreads();
  const float m = fmaxf(sred[0], sred[1]);
  __syncthreads();

  // pass 2: den
  float dp = 0.f;
  for (int e = lo + tid; e < hi; e += 128) dp += __expf(raw_attn[e] - m);
#pragma unroll
  for (int o = 32; o >= 1; o >>= 1) dp += __shfl_xor(dp, o, 64);
  if (t2 == 0) sred[g] = dp;
  __syncthreads();
  const float inv = (deg > 0) ? 1.0f / (sred[0] + sred[1]) : 0.0f;

  // pass 3: chunked gather; 8 edges in flight per wave
  float accx = 0.f, accy = 0.f;
  for (int c0 = 0; c0 < deg; c0 += 128) {
    const int n = min(128, deg - c0);
    __syncthreads();
    if (tid < n) {
      int e = lo + c0 + tid;
      float ex = __expf(raw_attn[e] - m) * inv;
      raw_attn[e] = ex;  // normalized attn output
      sex[tid] = ex;
      ssrc[tid] = src_idx[e];
    } else {
      sex[tid] = 0.f;
      ssrc[tid] = 0;
    }
    __syncthreads();
    const int nb = (n + 7) >> 3;
    for (int b = g; b < nb; b += 2) {
      const int base = b * 8;
#pragma unroll
      for (int j = 0; j < 8; j++) {
        float ex = sex[base + j];
        int s = ssrc[base + j];
        uint32 u = h_src_bf2[(size_t)s * 64 + t2];
        accx = fmaf(ex, bf_lo(u), accx);
        accy = fmaf(ex, bf_hi(u), accy);
      }
    }
  }
  if (g == 1) { sacc[t2][0] = accx; sacc[t2][1] = accy; }
  __syncthreads();
  if (g == 0) {
    float2 outv;
    outv.x = accx + sacc[t2][0];
    outv.y = accy + sacc[t2][1];
    *(float2*)(h_global + (size_t)v * D128 + t2 * 2) = outv;
  }
}

// ---------------------------------------------------------------------------
// out = [h_dst|h_global] @ Wo + bo; x = h_dst + out; y = LN(x)*gamma+beta
// ---------------------------------------------------------------------------
__global__ __launch_bounds__(128) void out_ln_kernel(
    const float* __restrict__ h_dst, const float* __restrict__ h_global,
    const float* __restrict__ Wo, const float* __restrict__ bo,
    const float* __restrict__ gamma, const float* __restrict__ beta,
    float* __restrict__ y, int N) {
  const int t = threadIdx.x;
  const int v0 = blockIdx.x * ROWS;
  __shared__ float xs[ROWS][260];
  __shared__ float redbuf[ROWS][2][2];

#pragma unroll
  for (int r = 0; r < ROWS; r++) {
    int v = v0 + r;
    float hd = 0.f, hg = 0.f;
    if (v < N) {
      hd = h_dst[(size_t)v * D128 + t];
      hg = h_global[(size_t)v * D128 + t];
    }
    xs[r][t] = hd;
    xs[r][128 + t] = hg;
  }
  __syncthreads();

  float o[ROWS];
#pragma unroll
  for (int r = 0; r < ROWS; r++) o[r] = bo[t];

  for (int k = 0; k < 256; k += 4) {
    float w0 = Wo[(size_t)(k + 0) * D128 + t];
    float w1 = Wo[(size_t)(k + 1) * D128 + t];
    float w2_ = Wo[(size_t)(k + 2) * D128 + t];
    float w3 = Wo[(size_t)(k + 3) * D128 + t];
#pragma unroll
    for (int r = 0; r < ROWS; r++) {
      float4 xv = *(const float4*)(&xs[r][k]);
      o[r] = fmaf(xv.x, w0, o[r]);
      o[r] = fmaf(xv.y, w1, o[r]);
      o[r] = fmaf(xv.z, w2_, o[r]);
      o[r] = fmaf(xv.w, w3, o[r]);
    }
  }

  const int lane = t & 63;
  const int wv = t >> 6;
  float xr[ROWS];
#pragma unroll
  for (int r = 0; r < ROWS; r++) {
    float x = xs[r][t] + o[r];
    xr[r] = x;
    float s1 = x, s2 = x * x;
#pragma unroll
    for (int off = 32; off >= 1; off >>= 1) {
      s1 += __shfl_xor(s1, off, 64);
      s2 += __shfl_xor(s2, off, 64);
    }
    if (lane == 0) { redbuf[r][wv][0] = s1; redbuf[r][wv][1] = s2; }
  }
  __syncthreads();

#pragma unroll
  for (int r = 0; r < ROWS; r++) {
    int v = v0 + r;
    if (v >= N) continue;
    float S1 = redbuf[r][0][0] + redbuf[r][1][0];
    float S2 = redbuf[r][0][1] + redbuf[r][1][1];
    float mu = S1 * (1.0f / 128.0f);
    float var = S2 * (1.0f / 128.0f) - mu * mu;
    float out = (xr[r] - mu) / sqrtf(var + 1e-5f) * gamma[t] + beta[t];
    y[(size_t)v * D128 + t] = out;
  }
}

extern "C" void kernel_launch(void* const* d_in, const int* in_sizes, int n_in,
                              void* d_out, int out_size, void* d_ws, size_t ws_size,
                              hipStream_t stream) {
  const float* h_src = (const float*)d_in[0];
  const float* h_dst = (const float*)d_in[1];
  const float* s_emb = (const float*)d_in[2];
  const float* ew    = (const float*)d_in[3];
  const int* src_idx = (const int*)d_in[4];
  const int* dst_idx = (const int*)d_in[5];
  const float* W1    = (const float*)d_in[6];
  const float* w2    = (const float*)d_in[7];
  const float* Wo    = (const float*)d_in[8];
  const float* bo    = (const float*)d_in[9];
  const float* gamma = (const float*)d_in[10];
  const float* beta  = (const float*)d_in[11];

  const int N_src = in_sizes[0] / D128;
  const int N_dst = in_sizes[1] / D128;
  const int E = in_sizes[3];

  float* out_y = (float*)d_out;                       // [N_dst*128]
  float* out_attn = out_y + (size_t)N_dst * D128;     // [E]

  // ws layout (uints hold 2 bf16):
  uint32* p_src_bf = (uint32*)d_ws;                           // N_src*64
  uint32* p_dst_bf = p_src_bf + (size_t)N_src * 64;           // N_dst*64
  uint32* h_src_bf = p_dst_bf + (size_t)N_dst * 64;           // N_src*64
  float* h_glob = (float*)(h_src_bf + (size_t)N_src * 64);    // N_dst*128
  int* seg_off = (int*)(h_glob + (size_t)N_dst * D128);       // N_dst+1
  unsigned short* Wt_bf = (unsigned short*)(seg_off + N_dst + 1 + 3);  // 2*128*128

  prep_w<<<128, 256, 0, stream>>>(W1, Wt_bf);
  seg_offsets_kernel<<<(E + 255) / 256, 256, 0, stream>>>(dst_idx, seg_off, E, N_dst);
  gemm_mfma<<<(N_src + 127) / 128, 256, 0, stream>>>(
      h_src, Wt_bf, (unsigned short*)p_src_bf, h_src_bf, N_src);
  gemm_mfma<<<(N_dst + 127) / 128, 256, 0, stream>>>(
      s_emb, Wt_bf + D128 * D128, (unsigned short*)p_dst_bf, (uint32*)nullptr, N_dst);
  edge_raw_kernel<<<(E + 15) / 16, 256, 0, stream>>>(p_src_bf, p_dst_bf, w2, ew,
                                                     src_idx, dst_idx, out_attn, E);
  dst_agg_kernel<<<N_dst, 128, 0, stream>>>(out_attn, h_src_bf, src_idx, seg_off,
                                            h_glob);
  out_ln_kernel<<<(N_dst + ROWS - 1) / ROWS, 128, 0, stream>>>(
      h_dst, h_glob, Wo, bo, gamma, beta, out_y, N_dst);
}

// Round 6
// 208.061 us; speedup vs baseline: 1.1007x; 1.1007x over previous
//
#include <hip/hip_runtime.h>
#include <math.h>

#define D128 128
#define ROWS 4

typedef unsigned int uint32;
typedef unsigned short ushort_t;
typedef short bf16x8 __attribute__((ext_vector_type(8)));
typedef float f32x4 __attribute__((ext_vector_type(4)));

// fp32 -> bf16 (RNE)
__device__ __forceinline__ ushort_t bf16_of(float x) {
  uint32 u = __float_as_uint(x);
  return (ushort_t)((u + 0x7fffu + ((u >> 16) & 1u)) >> 16);
}
__device__ __forceinline__ uint32 pack_bf2(float x, float y) {
  uint32 bx = __float_as_uint(x);
  uint32 by = __float_as_uint(y);
  bx = (bx + 0x7fffu + ((bx >> 16) & 1u)) >> 16;
  by = (by + 0x7fffu + ((by >> 16) & 1u)) & 0xffff0000u;
  return bx | by;
}
__device__ __forceinline__ float bf_lo(uint32 u) { return __uint_as_float(u << 16); }
__device__ __forceinline__ float bf_hi(uint32 u) { return __uint_as_float(u & 0xffff0000u); }

// tanh(x) = 1 - 2/(1+exp(2x)) via v_exp + v_rcp
__device__ __forceinline__ float fast_tanh(float x) {
  float e = __expf(2.0f * x);
  float r = __builtin_amdgcn_rcpf(1.0f + e);
  return fmaf(-2.0f, r, 1.0f);
}

// ---------------------------------------------------------------------------
// prep_w: W1 [256][128] fp32 -> Wt[2][128][128] bf16, Wt[h][n][k] = W1[h*128+k][n]
// ---------------------------------------------------------------------------
__global__ __launch_bounds__(256) void prep_w(const float* __restrict__ W1,
                                              ushort_t* __restrict__ Wt) {
  int t = blockIdx.x * 256 + threadIdx.x;   // 0..32767
  if (t >= 2 * D128 * D128) return;
  int h = t >> 14;
  int n = (t >> 7) & 127;
  int k = t & 127;
  Wt[t] = bf16_of(W1[(size_t)(h * D128 + k) * D128 + n]);
}

// ---------------------------------------------------------------------------
// convert_bf16: streaming fp32 -> bf16 for h_src (then s_emb), 8 floats/thread.
// ---------------------------------------------------------------------------
__global__ __launch_bounds__(256) void convert_bf16(
    const float* __restrict__ h_src, const float* __restrict__ s_emb,
    uint32* __restrict__ h_src_bf, uint32* __restrict__ s_emb_bf,
    int n_src_el, int n_tot_el) {
  int i = (blockIdx.x * 256 + threadIdx.x) * 8;
  if (i >= n_tot_el) return;
  const float* src;
  uint32* dst;
  if (i < n_src_el) { src = h_src + i; dst = h_src_bf + (i >> 1); }
  else { src = s_emb + (i - n_src_el); dst = s_emb_bf + ((i - n_src_el) >> 1); }
  float4 a = *(const float4*)src;
  float4 b = *(const float4*)(src + 4);
  uint4 p;
  p.x = pack_bf2(a.x, a.y);
  p.y = pack_bf2(a.z, a.w);
  p.z = pack_bf2(b.x, b.y);
  p.w = pack_bf2(b.z, b.w);
  *(uint4*)dst = p;
}

// ---------------------------------------------------------------------------
// seg_offsets: dst_idx sorted -> off[v] = first edge with dst >= v, off[N]=E.
// ---------------------------------------------------------------------------
__global__ __launch_bounds__(256) void seg_offsets_kernel(
    const int* __restrict__ dst_idx, int* __restrict__ off, int E, int N) {
  int e = blockIdx.x * 256 + threadIdx.x;
  if (e >= E) return;
  int d = dst_idx[e];
  int dprev = (e == 0) ? -1 : dst_idx[e - 1];
  for (int v = dprev + 1; v <= d; v++) off[v] = e;
  if (e == E - 1) {
    for (int v = d + 1; v <= N; v++) off[v] = E;
  }
}

// ---------------------------------------------------------------------------
// Merged GEMM: P = X @ W for two problems in one dispatch.
// bf16 in, bf16 out, MFMA 16x16x32. NO input LDS, NO pre-compute barrier:
// A-fragments (zero block-level reuse) and B-fragments (L2-hot 32 KB Wt)
// are direct per-lane 16-B global loads -> deep MLP, latency hidden by TLP.
// Epilogue: repack via LDS -> coalesced 8-B stores.
// 256 threads, 128-row tile; wave = 32 rows x 128 cols.
// ---------------------------------------------------------------------------
__global__ __launch_bounds__(256) void gemm_mfma(
    const ushort_t* __restrict__ Xa, const ushort_t* __restrict__ Xb,
    const ushort_t* __restrict__ Wt,
    ushort_t* __restrict__ Pa, ushort_t* __restrict__ Pb,
    int Ma, int Mb, int nblk_a) {
  __shared__ ushort_t Ys[128][132];   // 33792 B; 132-short stride (write-free banks)
  const int blk = blockIdx.x;
  const ushort_t* X;
  const ushort_t* W;
  ushort_t* P;
  int M, row0;
  if (blk < nblk_a) { X = Xa; P = Pa; W = Wt;         M = Ma; row0 = blk * 128; }
  else              { X = Xb; P = Pb; W = Wt + 16384; M = Mb; row0 = (blk - nblk_a) * 128; }

  const int tid = threadIdx.x;
  const int wave = tid >> 6;
  const int lane = tid & 63;
  const int m = lane & 15;
  const int quad = lane >> 4;

  const int ra0 = min(row0 + wave * 32 + m, M - 1);
  const int ra1 = min(row0 + wave * 32 + 16 + m, M - 1);

  f32x4 acc[2][8];
#pragma unroll
  for (int st = 0; st < 2; st++)
#pragma unroll
    for (int nt = 0; nt < 8; nt++) acc[st][nt] = (f32x4){0.f, 0.f, 0.f, 0.f};

#pragma unroll
  for (int kc = 0; kc < 4; kc++) {
    bf16x8 a0 = *(const bf16x8*)(X + (size_t)ra0 * D128 + kc * 32 + quad * 8);
    bf16x8 a1 = *(const bf16x8*)(X + (size_t)ra1 * D128 + kc * 32 + quad * 8);
#pragma unroll
    for (int nt = 0; nt < 8; nt++) {
      bf16x8 b = *(const bf16x8*)(W + (size_t)(nt * 16 + m) * D128 + kc * 32 + quad * 8);
      acc[0][nt] = __builtin_amdgcn_mfma_f32_16x16x32_bf16(a0, b, acc[0][nt], 0, 0, 0);
      acc[1][nt] = __builtin_amdgcn_mfma_f32_16x16x32_bf16(a1, b, acc[1][nt], 0, 0, 0);
    }
  }

  // C/D: col = lane&15, row = quad*4 + reg  ->  LDS repack
#pragma unroll
  for (int st = 0; st < 2; st++)
#pragma unroll
    for (int nt = 0; nt < 8; nt++)
#pragma unroll
      for (int r = 0; r < 4; r++)
        Ys[wave * 32 + st * 16 + quad * 4 + r][nt * 16 + m] = bf16_of(acc[st][nt][r]);
  __syncthreads();

  // coalesced store: 4096 8-B chunks, 16/thread
#pragma unroll
  for (int it = 0; it < 16; it++) {
    int f = tid + 256 * it;
    int row = f >> 5;
    int c = (f & 31) * 4;          // short offset within row
    int grow = row0 + row;
    if (grow < M) {
      uint2 v = *(const uint2*)(&Ys[row][c]);
      *(uint2*)(P + (size_t)grow * D128 + c) = v;
    }
  }
}

// ---------------------------------------------------------------------------
// 16 lanes per edge: raw[e] = tanh(p_src[src]+p_dst[dst]) . w2 * ew[e]
// ---------------------------------------------------------------------------
__global__ __launch_bounds__(256) void edge_raw_kernel(
    const uint32* __restrict__ p_src_bf, const uint32* __restrict__ p_dst_bf,
    const float* __restrict__ w2, const float* __restrict__ ew,
    const int* __restrict__ src_idx, const int* __restrict__ dst_idx,
    float* __restrict__ raw, int E) {
  __shared__ float sw2[128];
  const int tid = threadIdx.x;
  if (tid < 128) sw2[tid] = w2[tid];
  __syncthreads();
  const int sub = tid & 15;
  const int e = blockIdx.x * 16 + (tid >> 4);
  if (e >= E) return;
  const int s = src_idx[e];
  const int d = dst_idx[e];
  uint4 us = *(const uint4*)(p_src_bf + (size_t)s * 64 + sub * 4);
  uint4 ud = *(const uint4*)(p_dst_bf + (size_t)d * 64 + sub * 4);
  float4 wA = *(const float4*)(&sw2[sub * 8]);
  float4 wB = *(const float4*)(&sw2[sub * 8 + 4]);
  float acc;
  acc = fast_tanh(bf_lo(us.x) + bf_lo(ud.x)) * wA.x;
  acc = fmaf(fast_tanh(bf_hi(us.x) + bf_hi(ud.x)), wA.y, acc);
  acc = fmaf(fast_tanh(bf_lo(us.y) + bf_lo(ud.y)), wA.z, acc);
  acc = fmaf(fast_tanh(bf_hi(us.y) + bf_hi(ud.y)), wA.w, acc);
  acc = fmaf(fast_tanh(bf_lo(us.z) + bf_lo(ud.z)), wB.x, acc);
  acc = fmaf(fast_tanh(bf_hi(us.z) + bf_hi(ud.z)), wB.y, acc);
  acc = fmaf(fast_tanh(bf_lo(us.w) + bf_lo(ud.w)), wB.z, acc);
  acc = fmaf(fast_tanh(bf_hi(us.w) + bf_hi(ud.w)), wB.w, acc);
#pragma unroll
  for (int o = 1; o <= 8; o <<= 1) acc += __shfl_xor(acc, o, 64);
  if (sub == 0) raw[e] = acc * ew[e];
}

// ---------------------------------------------------------------------------
// one 128-thread block (2 waves) per dst. off[] gives edge range.
// ---------------------------------------------------------------------------
__global__ __launch_bounds__(128) void dst_agg_kernel(
    float* raw_attn, const uint32* __restrict__ h_src_bf2,
    const int* __restrict__ src_idx, const int* __restrict__ off,
    float* __restrict__ h_global) {
  const int v = blockIdx.x;
  const int tid = threadIdx.x;
  const int t2 = tid & 63;
  const int g = tid >> 6;
  const int lo = off[v], hi = off[v + 1];
  const int deg = hi - lo;

  __shared__ float sred[2];
  __shared__ float sex[128];
  __shared__ int ssrc[128];
  __shared__ float sacc[64][2];

  float lm = -INFINITY;
  for (int e = lo + tid; e < hi; e += 128) lm = fmaxf(lm, raw_attn[e]);
#pragma unroll
  for (int o = 32; o >= 1; o >>= 1) lm = fmaxf(lm, __shfl_xor(lm, o, 64));
  if (t2 == 0) sred[g] = lm;
  __syncthreads();
  const float m = fmaxf(sred[0], sred[1]);
  __syncthreads();

  float dp = 0.f;
  for (int e = lo + tid; e < hi; e += 128) dp += __expf(raw_attn[e] - m);
#pragma unroll
  for (int o = 32; o >= 1; o >>= 1) dp += __shfl_xor(dp, o, 64);
  if (t2 == 0) sred[g] = dp;
  __syncthreads();
  const float inv = (deg > 0) ? 1.0f / (sred[0] + sred[1]) : 0.0f;

  float accx = 0.f, accy = 0.f;
  for (int c0 = 0; c0 < deg; c0 += 128) {
    const int n = min(128, deg - c0);
    __syncthreads();
    if (tid < n) {
      int e = lo + c0 + tid;
      float ex = __expf(raw_attn[e] - m) * inv;
      raw_attn[e] = ex;  // normalized attn output
      sex[tid] = ex;
      ssrc[tid] = src_idx[e];
    } else {
      sex[tid] = 0.f;
      ssrc[tid] = 0;
    }
    __syncthreads();
    const int nb = (n + 7) >> 3;
    for (int b = g; b < nb; b += 2) {
      const int base = b * 8;
#pragma unroll
      for (int j = 0; j < 8; j++) {
        float ex = sex[base + j];
        int s = ssrc[base + j];
        uint32 u = h_src_bf2[(size_t)s * 64 + t2];
        accx = fmaf(ex, bf_lo(u), accx);
        accy = fmaf(ex, bf_hi(u), accy);
      }
    }
  }
  if (g == 1) { sacc[t2][0] = accx; sacc[t2][1] = accy; }
  __syncthreads();
  if (g == 0) {
    float2 outv;
    outv.x = accx + sacc[t2][0];
    outv.y = accy + sacc[t2][1];
    *(float2*)(h_global + (size_t)v * D128 + t2 * 2) = outv;
  }
}

// ---------------------------------------------------------------------------
// out = [h_dst|h_global] @ Wo + bo; x = h_dst + out; y = LN(x)*gamma+beta
// ---------------------------------------------------------------------------
__global__ __launch_bounds__(128) void out_ln_kernel(
    const float* __restrict__ h_dst, const float* __restrict__ h_global,
    const float* __restrict__ Wo, const float* __restrict__ bo,
    const float* __restrict__ gamma, const float* __restrict__ beta,
    float* __restrict__ y, int N) {
  const int t = threadIdx.x;
  const int v0 = blockIdx.x * ROWS;
  __shared__ float xs[ROWS][260];
  __shared__ float redbuf[ROWS][2][2];

#pragma unroll
  for (int r = 0; r < ROWS; r++) {
    int v = v0 + r;
    float hd = 0.f, hg = 0.f;
    if (v < N) {
      hd = h_dst[(size_t)v * D128 + t];
      hg = h_global[(size_t)v * D128 + t];
    }
    xs[r][t] = hd;
    xs[r][128 + t] = hg;
  }
  __syncthreads();

  float o[ROWS];
#pragma unroll
  for (int r = 0; r < ROWS; r++) o[r] = bo[t];

  for (int k = 0; k < 256; k += 4) {
    float w0 = Wo[(size_t)(k + 0) * D128 + t];
    float w1 = Wo[(size_t)(k + 1) * D128 + t];
    float w2_ = Wo[(size_t)(k + 2) * D128 + t];
    float w3 = Wo[(size_t)(k + 3) * D128 + t];
#pragma unroll
    for (int r = 0; r < ROWS; r++) {
      float4 xv = *(const float4*)(&xs[r][k]);
      o[r] = fmaf(xv.x, w0, o[r]);
      o[r] = fmaf(xv.y, w1, o[r]);
      o[r] = fmaf(xv.z, w2_, o[r]);
      o[r] = fmaf(xv.w, w3, o[r]);
    }
  }

  const int lane = t & 63;
  const int wv = t >> 6;
  float xr[ROWS];
#pragma unroll
  for (int r = 0; r < ROWS; r++) {
    float x = xs[r][t] + o[r];
    xr[r] = x;
    float s1 = x, s2 = x * x;
#pragma unroll
    for (int off = 32; off >= 1; off >>= 1) {
      s1 += __shfl_xor(s1, off, 64);
      s2 += __shfl_xor(s2, off, 64);
    }
    if (lane == 0) { redbuf[r][wv][0] = s1; redbuf[r][wv][1] = s2; }
  }
  __syncthreads();

#pragma unroll
  for (int r = 0; r < ROWS; r++) {
    int v = v0 + r;
    if (v >= N) continue;
    float S1 = redbuf[r][0][0] + redbuf[r][1][0];
    float S2 = redbuf[r][0][1] + redbuf[r][1][1];
    float mu = S1 * (1.0f / 128.0f);
    float var = S2 * (1.0f / 128.0f) - mu * mu;
    float out = (xr[r] - mu) / sqrtf(var + 1e-5f) * gamma[t] + beta[t];
    y[(size_t)v * D128 + t] = out;
  }
}

extern "C" void kernel_launch(void* const* d_in, const int* in_sizes, int n_in,
                              void* d_out, int out_size, void* d_ws, size_t ws_size,
                              hipStream_t stream) {
  const float* h_src = (const float*)d_in[0];
  const float* h_dst = (const float*)d_in[1];
  const float* s_emb = (const float*)d_in[2];
  const float* ew    = (const float*)d_in[3];
  const int* src_idx = (const int*)d_in[4];
  const int* dst_idx = (const int*)d_in[5];
  const float* W1    = (const float*)d_in[6];
  const float* w2    = (const float*)d_in[7];
  const float* Wo    = (const float*)d_in[8];
  const float* bo    = (const float*)d_in[9];
  const float* gamma = (const float*)d_in[10];
  const float* beta  = (const float*)d_in[11];

  const int N_src = in_sizes[0] / D128;
  const int N_dst = in_sizes[1] / D128;
  const int E = in_sizes[3];

  float* out_y = (float*)d_out;                       // [N_dst*128]
  float* out_attn = out_y + (size_t)N_dst * D128;     // [E]

  // ws layout (uints hold 2 bf16):
  uint32* p_src_bf = (uint32*)d_ws;                           // N_src*64
  uint32* p_dst_bf = p_src_bf + (size_t)N_src * 64;           // N_dst*64
  uint32* h_src_bf = p_dst_bf + (size_t)N_dst * 64;           // N_src*64
  float* h_glob = (float*)(h_src_bf + (size_t)N_src * 64);    // N_dst*128
  // s_emb_bf aliases h_glob: consumed by gemm BEFORE dst_agg writes h_glob
  uint32* s_emb_bf = (uint32*)h_glob;                         // N_dst*64
  int* seg_off = (int*)(h_glob + (size_t)N_dst * D128);       // N_dst+1
  ushort_t* Wt_bf = (ushort_t*)(seg_off + N_dst + 1 + 3);     // 2*128*128

  const int n_src_el = N_src * D128;
  const int n_tot_el = (N_src + N_dst) * D128;
  const int nblk_a = (N_src + 127) / 128;
  const int nblk_b = (N_dst + 127) / 128;

  prep_w<<<128, 256, 0, stream>>>(W1, Wt_bf);
  convert_bf16<<<(n_tot_el / 8 + 255) / 256, 256, 0, stream>>>(
      h_src, s_emb, h_src_bf, s_emb_bf, n_src_el, n_tot_el);
  seg_offsets_kernel<<<(E + 255) / 256, 256, 0, stream>>>(dst_idx, seg_off, E, N_dst);
  gemm_mfma<<<nblk_a + nblk_b, 256, 0, stream>>>(
      (const ushort_t*)h_src_bf, (const ushort_t*)s_emb_bf, Wt_bf,
      (ushort_t*)p_src_bf, (ushort_t*)p_dst_bf, N_src, N_dst, nblk_a);
  edge_raw_kernel<<<(E + 15) / 16, 256, 0, stream>>>(p_src_bf, p_dst_bf, w2, ew,
                                                     src_idx, dst_idx, out_attn, E);
  dst_agg_kernel<<<N_dst, 128, 0, stream>>>(out_attn, h_src_bf, src_idx, seg_off,
                                            h_glob);
  out_ln_kernel<<<(N_dst + ROWS - 1) / ROWS, 128, 0, stream>>>(
      h_dst, h_glob, Wo, bo, gamma, beta, out_y, N_dst);
}

// Round 7
// 204.743 us; speedup vs baseline: 1.1185x; 1.0162x over previous
//
#include <hip/hip_runtime.h>
#include <math.h>

#define D128 128
#define ROWS 8
#define SCAP 1024   // LDS score-buffer capacity (deg ~ Poisson(32); P(deg>1024)~0)

typedef unsigned int uint32;
typedef unsigned short ushort_t;
typedef short bf16x8 __attribute__((ext_vector_type(8)));
typedef float f32x4 __attribute__((ext_vector_type(4)));

// fp32 -> bf16 (RNE)
__device__ __forceinline__ ushort_t bf16_of(float x) {
  uint32 u = __float_as_uint(x);
  return (ushort_t)((u + 0x7fffu + ((u >> 16) & 1u)) >> 16);
}
__device__ __forceinline__ uint32 pack_bf2(float x, float y) {
  uint32 bx = __float_as_uint(x);
  uint32 by = __float_as_uint(y);
  bx = (bx + 0x7fffu + ((bx >> 16) & 1u)) >> 16;
  by = (by + 0x7fffu + ((by >> 16) & 1u)) & 0xffff0000u;
  return bx | by;
}
__device__ __forceinline__ float bf_lo(uint32 u) { return __uint_as_float(u << 16); }
__device__ __forceinline__ float bf_hi(uint32 u) { return __uint_as_float(u & 0xffff0000u); }

// tanh(x) = 1 - 2/(1+exp(2x)) via v_exp + v_rcp
__device__ __forceinline__ float fast_tanh(float x) {
  float e = __expf(2.0f * x);
  float r = __builtin_amdgcn_rcpf(1.0f + e);
  return fmaf(-2.0f, r, 1.0f);
}

// ---------------------------------------------------------------------------
// prep_all: one dispatch, block-range partitioned:
//   [0, nb_conv)            : fp32->bf16 convert of h_src then s_emb
//   [nb_conv, nb_conv+128)  : W1 transpose+convert -> Wt[2][128][128] bf16
//   [nb_conv+128, ...)      : segment offsets from sorted dst_idx
// ---------------------------------------------------------------------------
__global__ __launch_bounds__(256) void prep_all(
    const float* __restrict__ h_src, const float* __restrict__ s_emb,
    const float* __restrict__ W1, const int* __restrict__ dst_idx,
    uint32* __restrict__ h_src_bf, uint32* __restrict__ s_emb_bf,
    ushort_t* __restrict__ Wt, int* __restrict__ off,
    int n_src_el, int n_tot_el, int E, int N, int nb_conv) {
  const int b = blockIdx.x;
  const int tid = threadIdx.x;
  if (b < nb_conv) {
    int i = (b * 256 + tid) * 8;
    if (i >= n_tot_el) return;
    const float* src;
    uint32* dst;
    if (i < n_src_el) { src = h_src + i; dst = h_src_bf + (i >> 1); }
    else { src = s_emb + (i - n_src_el); dst = s_emb_bf + ((i - n_src_el) >> 1); }
    float4 a = *(const float4*)src;
    float4 c = *(const float4*)(src + 4);
    uint4 p;
    p.x = pack_bf2(a.x, a.y);
    p.y = pack_bf2(a.z, a.w);
    p.z = pack_bf2(c.x, c.y);
    p.w = pack_bf2(c.z, c.w);
    *(uint4*)dst = p;
  } else if (b < nb_conv + 128) {
    int t = (b - nb_conv) * 256 + tid;   // 0..32767
    int h = t >> 14;
    int n = (t >> 7) & 127;
    int k = t & 127;
    Wt[t] = bf16_of(W1[(size_t)(h * D128 + k) * D128 + n]);
  } else {
    int e = (b - nb_conv - 128) * 256 + tid;
    if (e >= E) return;
    int d = dst_idx[e];
    int dprev = (e == 0) ? -1 : dst_idx[e - 1];
    for (int v = dprev + 1; v <= d; v++) off[v] = e;
    if (e == E - 1) {
      for (int v = d + 1; v <= N; v++) off[v] = E;
    }
  }
}

// ---------------------------------------------------------------------------
// Merged GEMM: P = X @ W for two problems in one dispatch (bf16 MFMA,
// direct global loads, no input LDS/barrier; LDS repack epilogue).
// ---------------------------------------------------------------------------
__global__ __launch_bounds__(256) void gemm_mfma(
    const ushort_t* __restrict__ Xa, const ushort_t* __restrict__ Xb,
    const ushort_t* __restrict__ Wt,
    ushort_t* __restrict__ Pa, ushort_t* __restrict__ Pb,
    int Ma, int Mb, int nblk_a) {
  __shared__ ushort_t Ys[128][132];
  const int blk = blockIdx.x;
  const ushort_t* X;
  const ushort_t* W;
  ushort_t* P;
  int M, row0;
  if (blk < nblk_a) { X = Xa; P = Pa; W = Wt;         M = Ma; row0 = blk * 128; }
  else              { X = Xb; P = Pb; W = Wt + 16384; M = Mb; row0 = (blk - nblk_a) * 128; }

  const int tid = threadIdx.x;
  const int wave = tid >> 6;
  const int lane = tid & 63;
  const int m = lane & 15;
  const int quad = lane >> 4;

  const int ra0 = min(row0 + wave * 32 + m, M - 1);
  const int ra1 = min(row0 + wave * 32 + 16 + m, M - 1);

  f32x4 acc[2][8];
#pragma unroll
  for (int st = 0; st < 2; st++)
#pragma unroll
    for (int nt = 0; nt < 8; nt++) acc[st][nt] = (f32x4){0.f, 0.f, 0.f, 0.f};

#pragma unroll
  for (int kc = 0; kc < 4; kc++) {
    bf16x8 a0 = *(const bf16x8*)(X + (size_t)ra0 * D128 + kc * 32 + quad * 8);
    bf16x8 a1 = *(const bf16x8*)(X + (size_t)ra1 * D128 + kc * 32 + quad * 8);
#pragma unroll
    for (int nt = 0; nt < 8; nt++) {
      bf16x8 b = *(const bf16x8*)(W + (size_t)(nt * 16 + m) * D128 + kc * 32 + quad * 8);
      acc[0][nt] = __builtin_amdgcn_mfma_f32_16x16x32_bf16(a0, b, acc[0][nt], 0, 0, 0);
      acc[1][nt] = __builtin_amdgcn_mfma_f32_16x16x32_bf16(a1, b, acc[1][nt], 0, 0, 0);
    }
  }

#pragma unroll
  for (int st = 0; st < 2; st++)
#pragma unroll
    for (int nt = 0; nt < 8; nt++)
#pragma unroll
      for (int r = 0; r < 4; r++)
        Ys[wave * 32 + st * 16 + quad * 4 + r][nt * 16 + m] = bf16_of(acc[st][nt][r]);
  __syncthreads();

#pragma unroll
  for (int it = 0; it < 16; it++) {
    int f = tid + 256 * it;
    int row = f >> 5;
    int c = (f & 31) * 4;
    int grow = row0 + row;
    if (grow < M) {
      uint2 v = *(const uint2*)(&Ys[row][c]);
      *(uint2*)(P + (size_t)grow * D128 + c) = v;
    }
  }
}

// ---------------------------------------------------------------------------
// Fused attention + aggregation: one 256-thread block per dst node.
//  - p_dst row + w2 staged in LDS once per block
//  - scores (16 lanes/edge, gather p_src rows) -> LDS
//  - softmax max/den in LDS, contiguous normalized attn store
//  - aggregation: 8 h_src row-gathers in flight per wave
// Slow path (deg > SCAP): raw scores staged through attn_out global.
// ---------------------------------------------------------------------------
__global__ __launch_bounds__(256) void attn_agg_kernel(
    const uint32* __restrict__ p_src_bf, const uint32* __restrict__ p_dst_bf,
    const float* __restrict__ w2, const float* __restrict__ ew,
    const int* __restrict__ src_idx, const int* __restrict__ off,
    const uint32* __restrict__ h_src_bf2,
    float* __restrict__ attn_out, float* __restrict__ h_global) {
  const int v = blockIdx.x;
  const int tid = threadIdx.x;
  const int lo = off[v], hi = off[v + 1];
  const int deg = hi - lo;
  const int sub = tid & 15;
  const int eg16 = tid >> 4;
  const int t2 = tid & 63;
  const int wv = tid >> 6;

  __shared__ float sw2[128];
  __shared__ uint32 spd[64];
  __shared__ float sred[4];
  __shared__ float sex[SCAP];
  __shared__ int ssrc[SCAP];
  __shared__ float sacc[4][128];

  if (tid < 128) sw2[tid] = w2[tid];
  if (tid < 64) spd[tid] = p_dst_bf[(size_t)v * 64 + tid];
  __syncthreads();

  float accx = 0.f, accy = 0.f;
  float inv;

  if (deg <= SCAP) {
    // ---- fast path: everything in LDS ----
    for (int base = 0; base < deg; base += 16) {
      int ei = base + eg16;
      float acc = 0.f;
      int s = 0;
      if (ei < deg) {
        int e = lo + ei;
        s = src_idx[e];
        uint4 us = *(const uint4*)(p_src_bf + (size_t)s * 64 + sub * 4);
        uint4 ud = *(const uint4*)(&spd[sub * 4]);
        float4 wA = *(const float4*)(&sw2[sub * 8]);
        float4 wB = *(const float4*)(&sw2[sub * 8 + 4]);
        acc = fast_tanh(bf_lo(us.x) + bf_lo(ud.x)) * wA.x;
        acc = fmaf(fast_tanh(bf_hi(us.x) + bf_hi(ud.x)), wA.y, acc);
        acc = fmaf(fast_tanh(bf_lo(us.y) + bf_lo(ud.y)), wA.z, acc);
        acc = fmaf(fast_tanh(bf_hi(us.y) + bf_hi(ud.y)), wA.w, acc);
        acc = fmaf(fast_tanh(bf_lo(us.z) + bf_lo(ud.z)), wB.x, acc);
        acc = fmaf(fast_tanh(bf_hi(us.z) + bf_hi(ud.z)), wB.y, acc);
        acc = fmaf(fast_tanh(bf_lo(us.w) + bf_lo(ud.w)), wB.z, acc);
        acc = fmaf(fast_tanh(bf_hi(us.w) + bf_hi(ud.w)), wB.w, acc);
      }
#pragma unroll
      for (int o = 1; o <= 8; o <<= 1) acc += __shfl_xor(acc, o, 64);
      if (ei < deg && sub == 0) { sex[ei] = acc * ew[lo + ei]; ssrc[ei] = s; }
    }
    // pad to multiple of 8 for the batched aggregation
    const int pad = (deg + 7) & ~7;
    for (int i = deg + tid; i < pad; i += 256) { sex[i] = 0.f; ssrc[i] = 0; }
    __syncthreads();

    // max
    float lm = -INFINITY;
    for (int i = tid; i < deg; i += 256) lm = fmaxf(lm, sex[i]);
#pragma unroll
    for (int o = 32; o >= 1; o >>= 1) lm = fmaxf(lm, __shfl_xor(lm, o, 64));
    if (t2 == 0) sred[wv] = lm;
    __syncthreads();
    const float mx = fmaxf(fmaxf(sred[0], sred[1]), fmaxf(sred[2], sred[3]));
    __syncthreads();

    // exp + den (sex[i] -> exp value)
    float dp = 0.f;
    for (int i = tid; i < deg; i += 256) {
      float ex = __expf(sex[i] - mx);
      sex[i] = ex;
      dp += ex;
    }
#pragma unroll
    for (int o = 32; o >= 1; o >>= 1) dp += __shfl_xor(dp, o, 64);
    if (t2 == 0) sred[wv] = dp;
    __syncthreads();
    inv = (deg > 0) ? 1.0f / (((sred[0] + sred[1]) + (sred[2] + sred[3]))) : 0.0f;

    // contiguous normalized attn store
    for (int i = tid; i < deg; i += 256) attn_out[lo + i] = sex[i] * inv;

    // aggregation: 8 gathers in flight per wave
    const int nb = (deg + 7) >> 3;
    for (int b = wv; b < nb; b += 4) {
      const int base = b * 8;
#pragma unroll
      for (int j = 0; j < 8; j++) {
        float ex = sex[base + j];
        int s = ssrc[base + j];
        uint32 u = h_src_bf2[(size_t)s * 64 + t2];
        accx = fmaf(ex, bf_lo(u), accx);
        accy = fmaf(ex, bf_hi(u), accy);
      }
    }
  } else {
    // ---- slow path: raw scores staged via attn_out global (deg > SCAP) ----
    for (int base = 0; base < deg; base += 16) {
      int ei = base + eg16;
      float acc = 0.f;
      if (ei < deg) {
        int e = lo + ei;
        int s = src_idx[e];
        uint4 us = *(const uint4*)(p_src_bf + (size_t)s * 64 + sub * 4);
        uint4 ud = *(const uint4*)(&spd[sub * 4]);
        float4 wA = *(const float4*)(&sw2[sub * 8]);
        float4 wB = *(const float4*)(&sw2[sub * 8 + 4]);
        acc = fast_tanh(bf_lo(us.x) + bf_lo(ud.x)) * wA.x;
        acc = fmaf(fast_tanh(bf_hi(us.x) + bf_hi(ud.x)), wA.y, acc);
        acc = fmaf(fast_tanh(bf_lo(us.y) + bf_lo(ud.y)), wA.z, acc);
        acc = fmaf(fast_tanh(bf_hi(us.y) + bf_hi(ud.y)), wA.w, acc);
        acc = fmaf(fast_tanh(bf_lo(us.z) + bf_lo(ud.z)), wB.x, acc);
        acc = fmaf(fast_tanh(bf_hi(us.z) + bf_hi(ud.z)), wB.y, acc);
        acc = fmaf(fast_tanh(bf_lo(us.w) + bf_lo(ud.w)), wB.z, acc);
        acc = fmaf(fast_tanh(bf_hi(us.w) + bf_hi(ud.w)), wB.w, acc);
      }
#pragma unroll
      for (int o = 1; o <= 8; o <<= 1) acc += __shfl_xor(acc, o, 64);
      if (ei < deg && sub == 0) attn_out[lo + ei] = acc * ew[lo + ei];
    }
    __syncthreads();   // block-level visibility of global writes

    float lm = -INFINITY;
    for (int i = tid; i < deg; i += 256) lm = fmaxf(lm, attn_out[lo + i]);
#pragma unroll
    for (int o = 32; o >= 1; o >>= 1) lm = fmaxf(lm, __shfl_xor(lm, o, 64));
    if (t2 == 0) sred[wv] = lm;
    __syncthreads();
    const float mx = fmaxf(fmaxf(sred[0], sred[1]), fmaxf(sred[2], sred[3]));
    __syncthreads();

    float dp = 0.f;
    for (int i = tid; i < deg; i += 256) dp += __expf(attn_out[lo + i] - mx);
#pragma unroll
    for (int o = 32; o >= 1; o >>= 1) dp += __shfl_xor(dp, o, 64);
    if (t2 == 0) sred[wv] = dp;
    __syncthreads();
    inv = 1.0f / (((sred[0] + sred[1]) + (sred[2] + sred[3])));

    for (int w0 = 0; w0 < deg; w0 += SCAP) {
      const int wn = min(SCAP, deg - w0);
      __syncthreads();
      for (int i = tid; i < wn; i += 256) {
        float ex = __expf(attn_out[lo + w0 + i] - mx);
        sex[i] = ex;
        ssrc[i] = src_idx[lo + w0 + i];
        attn_out[lo + w0 + i] = ex * inv;
      }
      const int padw = (wn + 7) & ~7;
      for (int i = wn + tid; i < padw; i += 256) { sex[i] = 0.f; ssrc[i] = 0; }
      __syncthreads();
      const int nb = (wn + 7) >> 3;
      for (int b = wv; b < nb; b += 4) {
        const int base = b * 8;
#pragma unroll
        for (int j = 0; j < 8; j++) {
          float ex = sex[base + j];
          int s = ssrc[base + j];
          uint32 u = h_src_bf2[(size_t)s * 64 + t2];
          accx = fmaf(ex, bf_lo(u), accx);
          accy = fmaf(ex, bf_hi(u), accy);
        }
      }
    }
  }

  // cross-wave reduce + h_global store
  sacc[wv][t2 * 2] = accx;
  sacc[wv][t2 * 2 + 1] = accy;
  __syncthreads();
  if (tid < 128) {
    float s = (sacc[0][tid] + sacc[1][tid]) + (sacc[2][tid] + sacc[3][tid]);
    h_global[(size_t)v * D128 + tid] = s * inv;
  }
}

// ---------------------------------------------------------------------------
// out = [h_dst|h_global] @ Wo + bo; x = h_dst + out; y = LN(x)*gamma+beta
// 8 rows/block to amortize the 131 KB Wo stream.
// ---------------------------------------------------------------------------
__global__ __launch_bounds__(128) void out_ln_kernel(
    const float* __restrict__ h_dst, const float* __restrict__ h_global,
    const float* __restrict__ Wo, const float* __restrict__ bo,
    const float* __restrict__ gamma, const float* __restrict__ beta,
    float* __restrict__ y, int N) {
  const int t = threadIdx.x;
  const int v0 = blockIdx.x * ROWS;
  __shared__ float xs[ROWS][260];
  __shared__ float redbuf[ROWS][2][2];

#pragma unroll
  for (int r = 0; r < ROWS; r++) {
    int v = v0 + r;
    float hd = 0.f, hg = 0.f;
    if (v < N) {
      hd = h_dst[(size_t)v * D128 + t];
      hg = h_global[(size_t)v * D128 + t];
    }
    xs[r][t] = hd;
    xs[r][128 + t] = hg;
  }
  __syncthreads();

  float o[ROWS];
#pragma unroll
  for (int r = 0; r < ROWS; r++) o[r] = bo[t];

  for (int k = 0; k < 256; k += 4) {
    float w0 = Wo[(size_t)(k + 0) * D128 + t];
    float w1 = Wo[(size_t)(k + 1) * D128 + t];
    float w2_ = Wo[(size_t)(k + 2) * D128 + t];
    float w3 = Wo[(size_t)(k + 3) * D128 + t];
#pragma unroll
    for (int r = 0; r < ROWS; r++) {
      float4 xv = *(const float4*)(&xs[r][k]);
      o[r] = fmaf(xv.x, w0, o[r]);
      o[r] = fmaf(xv.y, w1, o[r]);
      o[r] = fmaf(xv.z, w2_, o[r]);
      o[r] = fmaf(xv.w, w3, o[r]);
    }
  }

  const int lane = t & 63;
  const int wv = t >> 6;
  float xr[ROWS];
#pragma unroll
  for (int r = 0; r < ROWS; r++) {
    float x = xs[r][t] + o[r];
    xr[r] = x;
    float s1 = x, s2 = x * x;
#pragma unroll
    for (int off = 32; off >= 1; off >>= 1) {
      s1 += __shfl_xor(s1, off, 64);
      s2 += __shfl_xor(s2, off, 64);
    }
    if (lane == 0) { redbuf[r][wv][0] = s1; redbuf[r][wv][1] = s2; }
  }
  __syncthreads();

#pragma unroll
  for (int r = 0; r < ROWS; r++) {
    int v = v0 + r;
    if (v >= N) continue;
    float S1 = redbuf[r][0][0] + redbuf[r][1][0];
    float S2 = redbuf[r][0][1] + redbuf[r][1][1];
    float mu = S1 * (1.0f / 128.0f);
    float var = S2 * (1.0f / 128.0f) - mu * mu;
    float out = (xr[r] - mu) / sqrtf(var + 1e-5f) * gamma[t] + beta[t];
    y[(size_t)v * D128 + t] = out;
  }
}

extern "C" void kernel_launch(void* const* d_in, const int* in_sizes, int n_in,
                              void* d_out, int out_size, void* d_ws, size_t ws_size,
                              hipStream_t stream) {
  const float* h_src = (const float*)d_in[0];
  const float* h_dst = (const float*)d_in[1];
  const float* s_emb = (const float*)d_in[2];
  const float* ew    = (const float*)d_in[3];
  const int* src_idx = (const int*)d_in[4];
  const int* dst_idx = (const int*)d_in[5];
  const float* W1    = (const float*)d_in[6];
  const float* w2    = (const float*)d_in[7];
  const float* Wo    = (const float*)d_in[8];
  const float* bo    = (const float*)d_in[9];
  const float* gamma = (const float*)d_in[10];
  const float* beta  = (const float*)d_in[11];

  const int N_src = in_sizes[0] / D128;
  const int N_dst = in_sizes[1] / D128;
  const int E = in_sizes[3];

  float* out_y = (float*)d_out;                       // [N_dst*128]
  float* out_attn = out_y + (size_t)N_dst * D128;     // [E]

  // ws layout (uints hold 2 bf16):
  uint32* p_src_bf = (uint32*)d_ws;                           // N_src*64
  uint32* p_dst_bf = p_src_bf + (size_t)N_src * 64;           // N_dst*64
  uint32* h_src_bf = p_dst_bf + (size_t)N_dst * 64;           // N_src*64
  float* h_glob = (float*)(h_src_bf + (size_t)N_src * 64);    // N_dst*128
  // s_emb_bf aliases h_glob: consumed by gemm BEFORE attn_agg writes h_glob
  uint32* s_emb_bf = (uint32*)h_glob;                         // N_dst*64
  int* seg_off = (int*)(h_glob + (size_t)N_dst * D128);       // N_dst+1
  ushort_t* Wt_bf = (ushort_t*)(seg_off + N_dst + 1 + 3);     // 2*128*128

  const int n_src_el = N_src * D128;
  const int n_tot_el = (N_src + N_dst) * D128;
  const int nblk_a = (N_src + 127) / 128;
  const int nblk_b = (N_dst + 127) / 128;
  const int nb_conv = (n_tot_el / 8 + 255) / 256;
  const int nb_seg = (E + 255) / 256;

  prep_all<<<nb_conv + 128 + nb_seg, 256, 0, stream>>>(
      h_src, s_emb, W1, dst_idx, h_src_bf, s_emb_bf, Wt_bf, seg_off,
      n_src_el, n_tot_el, E, N_dst, nb_conv);
  gemm_mfma<<<nblk_a + nblk_b, 256, 0, stream>>>(
      (const ushort_t*)h_src_bf, (const ushort_t*)s_emb_bf, Wt_bf,
      (ushort_t*)p_src_bf, (ushort_t*)p_dst_bf, N_src, N_dst, nblk_a);
  attn_agg_kernel<<<N_dst, 256, 0, stream>>>(
      p_src_bf, p_dst_bf, w2, ew, src_idx, seg_off, h_src_bf, out_attn, h_glob);
  out_ln_kernel<<<(N_dst + ROWS - 1) / ROWS, 128, 0, stream>>>(
      h_dst, h_glob, Wo, bo, gamma, beta, out_y, N_dst);
}